// Round 10
// baseline (448.440 us; speedup 1.0000x reference)
//
#include <hip/hip_runtime.h>
#include <math.h>

#define DDIM 1024
#define HDIM 128
#define BK 32

typedef float  f32x4  __attribute__((ext_vector_type(4)));
typedef __bf16 bf16x8 __attribute__((ext_vector_type(8)));

union BF2U { __bf16 h; ushort u; };

__constant__ int c_perms[6][3] = {{0,1,2},{0,2,1},{1,0,2},{1,2,0},{2,0,1},{2,1,0}};

__device__ __forceinline__ ushort f2bf(float f){
    BF2U c; c.h = (__bf16)f; return c.u;
}
// branch-free gelu: Abramowitz-Stegun 7.1.26 erf (|err| < 1.5e-7), HW exp
__device__ __forceinline__ float gelu_fast(float x){
    float a = fabsf(x) * 0.70710678118654752f;
    float t = __frcp_rn(fmaf(0.3275911f, a, 1.0f));
    float p = t * fmaf(t, fmaf(t, fmaf(t, fmaf(t, 1.061405429f, -1.453152027f),
                 1.421413741f), -0.284496736f), 0.254829592f);
    float y = 1.0f - p * __expf(-a * a);
    float er = copysignf(y, x);
    return 0.5f * x * (1.0f + er);
}

// ---------------- K0: weight images ----------------
// w1s: 32 chunks t (32 k each); halfword i = t*4096 + n*32 + kk  holds bf16(W1[t*32+kk][n])
// w2t: [n][k] bf16 swizzled: byte(n,k) = n*256 + ((k*2) ^ ((n&7)<<4))   (k2's LDS image)
__global__ __launch_bounds__(256) void k0_prep(const float* __restrict__ W1,
                                               const float* __restrict__ W2,
                                               ushort* __restrict__ w1s,
                                               ushort* __restrict__ w2t)
{
    int i = blockIdx.x * 256 + threadIdx.x;
    if (i < DDIM * HDIM) {
        int t = i >> 12, rem = i & 4095;
        int n = rem >> 5, kk = rem & 31;
        int k = t * 32 + kk;
        w1s[i] = f2bf(W1[(size_t)k * HDIM + n]);
    } else if (i < DDIM * HDIM + HDIM * HDIM) {
        int j = i - DDIM * HDIM;
        int k = j >> 7, n = j & 127;
        ushort b = f2bf(W2[(size_t)k * HDIM + n]);
        size_t off = (size_t)n * 256 + (size_t)(((k * 2) ^ ((n & 7) << 4)));
        w2t[off >> 1] = b;
    }
}

// ---------------- K1: base = bf16( seq @ W1[:1024] + b1 ) ----------------
// T3/T4: 3-deep global_load_lds ring; raw s_barrier + counted s_waitcnt vmcnt(6)
// (never 0 in main loop) so two stages stay in flight across every barrier.
__global__ __launch_bounds__(256, 2) void k1_gemm(const float* __restrict__ seq,
                                                  const ushort* __restrict__ w1s,
                                                  const float* __restrict__ b1,
                                                  ushort* __restrict__ baseo)
{
    __shared__ float As[3][4096];    // 16 KB each: [row 0..127][32 k f32]; 16B-unit u holds G[row][u ^ (row&7)]
    __shared__ char  Bs[3][8192];    // 8 KB each: linear copy of w1s chunk (n*32+kk halfwords)
    const int t = threadIdx.x;
    const int wid = t >> 6, lane = t & 63;
    const int g = lane >> 4, ln = lane & 15;
    const size_t row0 = (size_t)blockIdx.x * 128;

    // A staging coords: issue j covers rows j*32 + wid*8 + (lane>>3)
    const int srow = wid * 8 + (lane >> 3);
    const int scolb = ((lane & 7) * 16) ^ ((lane >> 3) << 4);   // XOR'd source byte-in-row
    const int sldsw = wid * 1024;                                // wave-uniform LDS offset
    const int blane = lane * 16;                                 // per-lane B source offset

    // 6 global_load_lds per wave per STAGE (4 A + 2 B), in fixed program order.
#define STAGE(BUF, TT) do { \
    _Pragma("unroll") \
    for (int j_ = 0; j_ < 4; ++j_) { \
        const char* ga_ = (const char*)(seq + (row0 + j_ * 32 + srow) * DDIM + (TT) * BK) + scolb; \
        char* la_ = (char*)&As[BUF][0] + j_ * 4096 + sldsw; \
        __builtin_amdgcn_global_load_lds((const __attribute__((address_space(1))) void*)ga_, \
                                         (__attribute__((address_space(3))) void*)la_, 16, 0, 0); \
    } \
    _Pragma("unroll") \
    for (int i_ = 0; i_ < 2; ++i_) { \
        const char* gb_ = (const char*)w1s + (size_t)(TT) * 8192 + i_ * 4096 + sldsw + blane; \
        char* lb_ = &Bs[BUF][0] + i_ * 4096 + sldsw; \
        __builtin_amdgcn_global_load_lds((const __attribute__((address_space(1))) void*)gb_, \
                                         (__attribute__((address_space(3))) void*)lb_, 16, 0, 0); \
    } } while (0)

#define COMPUTE(BUF) do { \
    bf16x8 af[2]; \
    _Pragma("unroll") \
    for (int mf = 0; mf < 2; ++mf) { \
        const int row = wid * 32 + mf * 16 + ln; \
        const int sw = (row & 7) << 4; \
        f32x4 x0 = *reinterpret_cast<const f32x4*>((const char*)&As[BUF][0] + row * 128 + ((g * 32 +  0) ^ sw)); \
        f32x4 x1 = *reinterpret_cast<const f32x4*>((const char*)&As[BUF][0] + row * 128 + ((g * 32 + 16) ^ sw)); \
        af[mf][0] = (__bf16)x0[0]; af[mf][1] = (__bf16)x0[1]; \
        af[mf][2] = (__bf16)x0[2]; af[mf][3] = (__bf16)x0[3]; \
        af[mf][4] = (__bf16)x1[0]; af[mf][5] = (__bf16)x1[1]; \
        af[mf][6] = (__bf16)x1[2]; af[mf][7] = (__bf16)x1[3]; \
    } \
    const ushort* btile = reinterpret_cast<const ushort*>(&Bs[BUF][0]); \
    _Pragma("unroll") \
    for (int nf = 0; nf < 8; ++nf) { \
        bf16x8 bb = *reinterpret_cast<const bf16x8*>(btile + nf * 512 + ln * 32 + g * 8); \
        acc[0][nf] = __builtin_amdgcn_mfma_f32_16x16x32_bf16(af[0], bb, acc[0][nf], 0, 0, 0); \
        acc[1][nf] = __builtin_amdgcn_mfma_f32_16x16x32_bf16(af[1], bb, acc[1][nf], 0, 0, 0); \
    } } while (0)

#define WAITBAR(N) do { \
    asm volatile("s_waitcnt vmcnt(" #N ")" ::: "memory"); \
    __builtin_amdgcn_sched_barrier(0); \
    __builtin_amdgcn_s_barrier(); \
    __builtin_amdgcn_sched_barrier(0); } while (0)

    f32x4 acc[2][8];
#pragma unroll
    for (int m = 0; m < 2; ++m)
#pragma unroll
        for (int n = 0; n < 8; ++n) acc[m][n] = (f32x4){0.f, 0.f, 0.f, 0.f};

    STAGE(0, 0);
    STAGE(1, 1);

    int cur = 0, nxt2 = 2;
    for (int tt = 0; tt < 30; ++tt) {
        WAITBAR(6);                    // own tile-tt loads done (12 out -> wait to 6), then barrier = all waves'
        STAGE(nxt2, tt + 2);           // overwrites tile tt-1's buf: safe, barrier proved all reads done
        COMPUTE(cur);
        cur  = (cur  == 2) ? 0 : cur  + 1;
        nxt2 = (nxt2 == 2) ? 0 : nxt2 + 1;
    }
    WAITBAR(6);                        // tile 30 resident (31's 6 still in flight)
    COMPUTE(cur);
    cur = (cur == 2) ? 0 : cur + 1;
    WAITBAR(0);                        // tile 31 resident
    COMPUTE(cur);

#undef WAITBAR
#undef COMPUTE
#undef STAGE

    float b1v[8];
#pragma unroll
    for (int nf = 0; nf < 8; ++nf) b1v[nf] = b1[nf * 16 + ln];
#pragma unroll
    for (int mf = 0; mf < 2; ++mf)
#pragma unroll
        for (int nf = 0; nf < 8; ++nf)
#pragma unroll
            for (int r = 0; r < 4; ++r) {
                int row = wid * 32 + mf * 16 + g * 4 + r;   // C/D: col=lane&15, row=(lane>>4)*4+reg [m89]
                int col = nf * 16 + ln;
                baseo[(row0 + row) * HDIM + col] = f2bf(acc[mf][nf][r] + b1v[nf]);
            }
}

// ---------------- K2: 3-step recurrence; 4 waves x 16 rows; layer2 via MFMA, no barriers in step loop ----------------
__global__ __launch_bounds__(256) void k2_steps(
    const ushort* __restrict__ basei,   // [B][128] bf16 (includes b1)
    const ushort* __restrict__ w2t,     // swizzled W2^T image, 32KB
    const float* __restrict__ freq,
    const float* __restrict__ pres,
    const float* __restrict__ rmask,
    const int*   __restrict__ pidx,
    const float* __restrict__ W1,       // rows 1024..1035 (state + one-hot)
    const float* __restrict__ b2,
    const float* __restrict__ W3,
    const float* __restrict__ b3,
    float* __restrict__ dec_f,
    float* __restrict__ dec_p,
    float* __restrict__ partials)
{
    __shared__ char  W2s[32768];
    __shared__ float W1es[12][128];
    __shared__ float stl[64][2];     // per-row (act_f, act_p) exchange, wave-private rows
    __shared__ float redl[8];

    const int t = threadIdx.x;
    const int wid = t >> 6, lane = t & 63;
    const int g = lane >> 4, ln = lane & 15;

#pragma unroll
    for (int i = 0; i < 8; ++i) {
        uint4 v = *reinterpret_cast<const uint4*>((const char*)w2t + t * 16 + i * 4096);
        *reinterpret_cast<uint4*>(W2s + t * 16 + i * 4096) = v;
    }
    for (int i = t; i < 12 * 128; i += 256)
        W1es[i >> 7][i & 127] = W1[(size_t)(DDIM + (i >> 7)) * HDIM + (i & 127)];
    __syncthreads();

    const int rowLocal = wid * 16 + ln;                 // h1 row this lane computes (cols split by g)
    const size_t R_h = (size_t)blockIdx.x * 64 + rowLocal;
    const int pidx_h = pidx[R_h];

    float basef[32];                                     // cols c = ks*32 + g*8 + j
    {
        const ushort* brow = basei + R_h * HDIM;
#pragma unroll
        for (int ks = 0; ks < 4; ++ks) {
            bf16x8 v = *reinterpret_cast<const bf16x8*>(brow + ks * 32 + g * 8);
#pragma unroll
            for (int j = 0; j < 8; ++j) basef[ks * 8 + j] = (float)v[j];
        }
    }
    float scon[32];                                      // incremental state @ W1e contribution
#pragma unroll
    for (int i = 0; i < 32; ++i) scon[i] = 0.f;

    const bool owner = (ln < 4);
    const int rloc_own = wid * 16 + g * 4 + ln;
    const size_t R_own = (size_t)blockIdx.x * 64 + rloc_own;
    int pio = 0;
    float ffo[3] = {0,0,0}, ppo[3] = {0,0,0}, mmo[3] = {0,0,0};
    if (owner) {
        pio = pidx[R_own];
#pragma unroll
        for (int q = 0; q < 3; ++q) {
            ffo[q] = freq[R_own * 3 + q];
            ppo[q] = pres[R_own * 3 + q];
            mmo[q] = rmask[R_own * 3 + q];
        }
    }
    float b2v[8], w30[8], w31[8];
#pragma unroll
    for (int nf = 0; nf < 8; ++nf) {
        b2v[nf] = b2[nf * 16 + ln];
        w30[nf] = W3[(nf * 16 + ln) * 2 + 0];
        w31[nf] = W3[(nf * 16 + ln) * 2 + 1];
    }
    const float b30 = b3[0], b31 = b3[1];

    float lossAcc = 0.f, maskAcc = 0.f;

    for (int s = 0; s < 3; ++s) {
        const int ridx_h = c_perms[pidx_h][s];
        // ---- layer 1 build + gelu + pack into A fragments
        bf16x8 afr[4];
#pragma unroll
        for (int ks = 0; ks < 4; ++ks) {
            const float* ohp = &W1es[9 + ridx_h][ks * 32 + g * 8];
            f32x4 o0 = *reinterpret_cast<const f32x4*>(ohp);
            f32x4 o1 = *reinterpret_cast<const f32x4*>(ohp + 4);
#pragma unroll
            for (int j = 0; j < 4; ++j) {
                afr[ks][j]     = (__bf16)gelu_fast(basef[ks * 8 + j]     + scon[ks * 8 + j]     + o0[j]);
                afr[ks][4 + j] = (__bf16)gelu_fast(basef[ks * 8 + 4 + j] + scon[ks * 8 + 4 + j] + o1[j]);
            }
        }
        // ---- layer 2: MFMA over K=128
        f32x4 acc2[8];
#pragma unroll
        for (int nf = 0; nf < 8; ++nf) acc2[nf] = (f32x4){0.f, 0.f, 0.f, 0.f};
#pragma unroll
        for (int ks = 0; ks < 4; ++ks) {
#pragma unroll
            for (int nf = 0; nf < 8; ++nf) {
                const int n = nf * 16 + ln;
                bf16x8 bb = *reinterpret_cast<const bf16x8*>(W2s + n * 256 + ((ks * 64 + g * 16) ^ ((n & 7) << 4)));
                acc2[nf] = __builtin_amdgcn_mfma_f32_16x16x32_bf16(afr[ks], bb, acc2[nf], 0, 0, 0);
            }
        }
        // ---- h2 gelu + layer-3 partials (rows g*4+r, cols nf*16+ln)
        float p0[4] = {0, 0, 0, 0}, p1[4] = {0, 0, 0, 0};
#pragma unroll
        for (int nf = 0; nf < 8; ++nf) {
#pragma unroll
            for (int r = 0; r < 4; ++r) {
                float h2 = gelu_fast(acc2[nf][r] + b2v[nf]);
                p0[r] += h2 * w30[nf];
                p1[r] += h2 * w31[nf];
            }
        }
#pragma unroll
        for (int mk = 1; mk < 16; mk <<= 1) {
#pragma unroll
            for (int r = 0; r < 4; ++r) {
                p0[r] += __shfl_xor(p0[r], mk);
                p1[r] += __shfl_xor(p1[r], mk);
            }
        }
        // ---- per-row epilogue on owner lanes (rows g*4 + ln, ln<4)
        if (owner) {
            const int ridx_o = c_perms[pio][s];
            float pf = ((ln == 0) ? p0[0] : (ln == 1) ? p0[1] : (ln == 2) ? p0[2] : p0[3]) + b30;
            float z  = ((ln == 0) ? p1[0] : (ln == 1) ? p1[1] : (ln == 2) ? p1[2] : p1[3]) + b31;
            float gt_f = (ridx_o == 0) ? ffo[0] : (ridx_o == 1) ? ffo[1] : ffo[2];
            float gt_p = (ridx_o == 0) ? ppo[0] : (ridx_o == 1) ? ppo[1] : ppo[2];
            float m    = (ridx_o == 0) ? mmo[0] : (ridx_o == 1) ? mmo[1] : mmo[2];
            float d = pf - gt_f;
            float pl = (fmaxf(z, 0.f) - z * gt_p + __logf(1.0f + __expf(-fabsf(z)))) * m;
            lossAcc += d * d * m + pl;
            maskAcc += m;
            bool msk = m > 0.5f;
            float act_f = msk ? pf : gt_f;
            float act_p = msk ? (1.f / (1.f + __expf(-z))) : gt_p;
            stl[rloc_own][0] = act_f;
            stl[rloc_own][1] = act_p;
            dec_f[R_own * 3 + ridx_o] = act_f;
            dec_p[R_own * 3 + ridx_o] = act_p;
        }
        // ---- incremental state contribution update (same wave: DS ops in order)
        if (s < 2) {
            float af = stl[rowLocal][0];
            float ap = stl[rowLocal][1];
            const float* w0r = &W1es[ridx_h * 3 + 0][0];
            const float* w1r = &W1es[ridx_h * 3 + 1][0];
            const float* w2r = &W1es[ridx_h * 3 + 2][0];
#pragma unroll
            for (int ks = 0; ks < 4; ++ks) {
                const int c0 = ks * 32 + g * 8;
                f32x4 a0 = *reinterpret_cast<const f32x4*>(w0r + c0);
                f32x4 a1 = *reinterpret_cast<const f32x4*>(w0r + c0 + 4);
                f32x4 b0 = *reinterpret_cast<const f32x4*>(w1r + c0);
                f32x4 b1x = *reinterpret_cast<const f32x4*>(w1r + c0 + 4);
                f32x4 c0v = *reinterpret_cast<const f32x4*>(w2r + c0);
                f32x4 c1v = *reinterpret_cast<const f32x4*>(w2r + c0 + 4);
#pragma unroll
                for (int j = 0; j < 4; ++j) {
                    scon[ks * 8 + j]     += af * a0[j] + ap * b0[j]  + c0v[j];
                    scon[ks * 8 + 4 + j] += af * a1[j] + ap * b1x[j] + c1v[j];
                }
            }
        }
    }
    // ---- deterministic loss reduction
#pragma unroll
    for (int mk = 1; mk < 64; mk <<= 1) {
        lossAcc += __shfl_xor(lossAcc, mk);
        maskAcc += __shfl_xor(maskAcc, mk);
    }
    if (lane == 0) { redl[wid * 2] = lossAcc; redl[wid * 2 + 1] = maskAcc; }
    __syncthreads();
    if (t == 0) {
        float ls = 0.f, ms = 0.f;
#pragma unroll
        for (int w = 0; w < 4; ++w) { ls += redl[w * 2]; ms += redl[w * 2 + 1]; }
        partials[2 * (size_t)blockIdx.x]     = ls;
        partials[2 * (size_t)blockIdx.x + 1] = ms;
    }
}

// ---------------- K3: deterministic final reduction ----------------
__global__ __launch_bounds__(256) void k3_reduce(const float* __restrict__ partials,
                                                 int nb, float* __restrict__ out)
{
    __shared__ float sl[256], sm[256];
    int t = threadIdx.x;
    float ls = 0.f, ms = 0.f;
    for (int i = t; i < nb; i += 256) { ls += partials[2 * i]; ms += partials[2 * i + 1]; }
    sl[t] = ls; sm[t] = ms;
    __syncthreads();
    for (int s = 128; s > 0; s >>= 1) {
        if (t < s) { sl[t] += sl[t + s]; sm[t] += sm[t + s]; }
        __syncthreads();
    }
    if (t == 0) out[0] = sl[0] / (sm[0] + 1e-8f);
}

extern "C" void kernel_launch(void* const* d_in, const int* in_sizes, int n_in,
                              void* d_out, int out_size, void* d_ws, size_t ws_size,
                              hipStream_t stream) {
    const float* seq   = (const float*)d_in[0];
    const float* freq  = (const float*)d_in[1];
    const float* pres  = (const float*)d_in[2];
    const float* rmask = (const float*)d_in[3];
    const int*   pidx  = (const int*)d_in[4];
    const float* W1    = (const float*)d_in[5];
    const float* b1    = (const float*)d_in[6];
    const float* W2    = (const float*)d_in[7];
    const float* b2    = (const float*)d_in[8];
    const float* W3    = (const float*)d_in[9];
    const float* b3    = (const float*)d_in[10];

    int B = in_sizes[4];
    float* out   = (float*)d_out;
    float* dec_f = out + 1;
    float* dec_p = out + 1 + (size_t)B * 3;

    char* ws = (char*)d_ws;
    float*  partials = (float*)ws;                        // 16 KB
    ushort* w1s  = (ushort*)(ws + 16384);                 // 256 KB
    ushort* w2t  = (ushort*)(ws + 16384 + 262144);        // 32 KB
    ushort* base = (ushort*)(ws + 16384 + 262144 + 32768);// 33.5 MB

    k0_prep<<<(DDIM * HDIM + HDIM * HDIM + 255) / 256, 256, 0, stream>>>(W1, W2, w1s, w2t);
    // MEASUREMENT ROUND: k1 launched TWICE (idempotent — writes identical `base` both
    // times). Total dur = k0 + 2*k1 + k2 + k3; delta vs R9's 301 us isolates k1.
    k1_gemm<<<B / 128, 256, 0, stream>>>(seq, w1s, b1, base);
    k1_gemm<<<B / 128, 256, 0, stream>>>(seq, w1s, b1, base);
    k2_steps<<<B / 64, 256, 0, stream>>>(base, w2t, freq, pres, rmask, pidx,
                                         W1, b2, W3, b3, dec_f, dec_p, partials);
    k3_reduce<<<1, 256, 0, stream>>>(partials, B / 64, out);
}

// Round 11
// 202.399 us; speedup vs baseline: 2.2156x; 2.2156x over previous
//
#include <hip/hip_runtime.h>
#include <math.h>

#define DDIM 1024
#define HDIM 128
#define BK 32

typedef float  f32x4  __attribute__((ext_vector_type(4)));
typedef __bf16 bf16x8 __attribute__((ext_vector_type(8)));

union BF2U { __bf16 h; ushort u; };

__constant__ int c_perms[6][3] = {{0,1,2},{0,2,1},{1,0,2},{1,2,0},{2,0,1},{2,1,0}};

__device__ __forceinline__ ushort f2bf(float f){
    BF2U c; c.h = (__bf16)f; return c.u;
}
// branch-free gelu: Abramowitz-Stegun 7.1.26 erf (|err| < 1.5e-7), HW exp
__device__ __forceinline__ float gelu_fast(float x){
    float a = fabsf(x) * 0.70710678118654752f;
    float t = __frcp_rn(fmaf(0.3275911f, a, 1.0f));
    float p = t * fmaf(t, fmaf(t, fmaf(t, fmaf(t, 1.061405429f, -1.453152027f),
                 1.421413741f), -0.284496736f), 0.254829592f);
    float y = 1.0f - p * __expf(-a * a);
    float er = copysignf(y, x);
    return 0.5f * x * (1.0f + er);
}

// ---------------- K0: weight images (unchanged) ----------------
// w1s: 32 chunks t; halfword i = t*4096 + n*32 + kk = bf16(W1[t*32+kk][n])
// w2t: [n][k] bf16 swizzled: byte(n,k) = n*256 + ((k*2) ^ ((n&7)<<4))
__global__ __launch_bounds__(256) void k0_prep(const float* __restrict__ W1,
                                               const float* __restrict__ W2,
                                               ushort* __restrict__ w1s,
                                               ushort* __restrict__ w2t)
{
    int i = blockIdx.x * 256 + threadIdx.x;
    if (i < DDIM * HDIM) {
        int t = i >> 12, rem = i & 4095;
        int n = rem >> 5, kk = rem & 31;
        int k = t * 32 + kk;
        w1s[i] = f2bf(W1[(size_t)k * HDIM + n]);
    } else if (i < DDIM * HDIM + HDIM * HDIM) {
        int j = i - DDIM * HDIM;
        int k = j >> 7, n = j & 127;
        ushort b = f2bf(W2[(size_t)k * HDIM + n]);
        size_t off = (size_t)n * 256 + (size_t)(((k * 2) ^ ((n & 7) << 4)));
        w2t[off >> 1] = b;
    }
}

// ---------------- KF: fused GEMM (R9 ring) + 3-step recurrence ----------------
// 256 thr / 4 waves / 128 rows per block. One 72KB LDS arena:
//   phase A: As[3]@0 (3x16KB), Bs[3]@49152 (3x8KB)   [R9 k1 verbatim]
//   phase B (after barrier, aliased): Ct@0 (32KB swizzled C tile),
//   W2s@32768 (32KB), W1es@65536 (6KB), stl@71680, redl@72192
__global__ __launch_bounds__(256, 2) void kf_fused(
    const float* __restrict__ seq,
    const ushort* __restrict__ w1s,
    const ushort* __restrict__ w2t,
    const float* __restrict__ freq,
    const float* __restrict__ pres,
    const float* __restrict__ rmask,
    const int*   __restrict__ pidx,
    const float* __restrict__ W1,
    const float* __restrict__ b1,
    const float* __restrict__ b2,
    const float* __restrict__ W3,
    const float* __restrict__ b3,
    float* __restrict__ dec_f,
    float* __restrict__ dec_p,
    float* __restrict__ partials)
{
    __shared__ __align__(16) char lds[73728];
    const int t = threadIdx.x;
    const int wid = t >> 6, lane = t & 63;
    const int g = lane >> 4, ln = lane & 15;
    const size_t row0 = (size_t)blockIdx.x * 128;

    char* const As0 = lds;                 // + buf*16384
    char* const Bs0 = lds + 49152;         // + buf*8192

    const int srow = wid * 8 + (lane >> 3);
    const int scolb = ((lane & 7) * 16) ^ ((lane >> 3) << 4);
    const int sldsw = wid * 1024;
    const int blane = lane * 16;

#define STAGE(BUF, TT) do { \
    _Pragma("unroll") \
    for (int j_ = 0; j_ < 4; ++j_) { \
        const char* ga_ = (const char*)(seq + (row0 + j_ * 32 + srow) * DDIM + (TT) * BK) + scolb; \
        char* la_ = As0 + (BUF) * 16384 + j_ * 4096 + sldsw; \
        __builtin_amdgcn_global_load_lds((const __attribute__((address_space(1))) void*)ga_, \
                                         (__attribute__((address_space(3))) void*)la_, 16, 0, 0); \
    } \
    _Pragma("unroll") \
    for (int i_ = 0; i_ < 2; ++i_) { \
        const char* gb_ = (const char*)w1s + (size_t)(TT) * 8192 + i_ * 4096 + sldsw + blane; \
        char* lb_ = Bs0 + (BUF) * 8192 + i_ * 4096 + sldsw; \
        __builtin_amdgcn_global_load_lds((const __attribute__((address_space(1))) void*)gb_, \
                                         (__attribute__((address_space(3))) void*)lb_, 16, 0, 0); \
    } } while (0)

#define COMPUTE(BUF) do { \
    bf16x8 af[2]; \
    _Pragma("unroll") \
    for (int mf = 0; mf < 2; ++mf) { \
        const int row = wid * 32 + mf * 16 + ln; \
        const int sw = (row & 7) << 4; \
        f32x4 x0 = *reinterpret_cast<const f32x4*>(As0 + (BUF) * 16384 + row * 128 + ((g * 32 +  0) ^ sw)); \
        f32x4 x1 = *reinterpret_cast<const f32x4*>(As0 + (BUF) * 16384 + row * 128 + ((g * 32 + 16) ^ sw)); \
        af[mf][0] = (__bf16)x0[0]; af[mf][1] = (__bf16)x0[1]; \
        af[mf][2] = (__bf16)x0[2]; af[mf][3] = (__bf16)x0[3]; \
        af[mf][4] = (__bf16)x1[0]; af[mf][5] = (__bf16)x1[1]; \
        af[mf][6] = (__bf16)x1[2]; af[mf][7] = (__bf16)x1[3]; \
    } \
    const ushort* btile = reinterpret_cast<const ushort*>(Bs0 + (BUF) * 8192); \
    _Pragma("unroll") \
    for (int nf = 0; nf < 8; ++nf) { \
        bf16x8 bb = *reinterpret_cast<const bf16x8*>(btile + nf * 512 + ln * 32 + g * 8); \
        acc[0][nf] = __builtin_amdgcn_mfma_f32_16x16x32_bf16(af[0], bb, acc[0][nf], 0, 0, 0); \
        acc[1][nf] = __builtin_amdgcn_mfma_f32_16x16x32_bf16(af[1], bb, acc[1][nf], 0, 0, 0); \
    } } while (0)

#define WAITBAR(N) do { \
    asm volatile("s_waitcnt vmcnt(" #N ")" ::: "memory"); \
    __builtin_amdgcn_sched_barrier(0); \
    __builtin_amdgcn_s_barrier(); \
    __builtin_amdgcn_sched_barrier(0); } while (0)

    f32x4 acc[2][8];
#pragma unroll
    for (int m = 0; m < 2; ++m)
#pragma unroll
        for (int n = 0; n < 8; ++n) acc[m][n] = (f32x4){0.f, 0.f, 0.f, 0.f};

    STAGE(0, 0);
    STAGE(1, 1);
    int cur = 0, nxt2 = 2;
    for (int tt = 0; tt < 30; ++tt) {
        WAITBAR(6);
        STAGE(nxt2, tt + 2);
        COMPUTE(cur);
        cur  = (cur  == 2) ? 0 : cur  + 1;
        nxt2 = (nxt2 == 2) ? 0 : nxt2 + 1;
    }
    WAITBAR(6);
    COMPUTE(cur);
    cur = (cur == 2) ? 0 : cur + 1;
    WAITBAR(0);
    COMPUTE(cur);
#undef WAITBAR
#undef COMPUTE
#undef STAGE

    __syncthreads();                       // all As/Bs reads done -> safe to alias

    // ---- C epilogue -> swizzled LDS tile Ct: byte(row,col) = row*256 + ((col*2)^((row&7)<<4))
    {
        float b1v[8];
#pragma unroll
        for (int nf = 0; nf < 8; ++nf) b1v[nf] = b1[nf * 16 + ln];
#pragma unroll
        for (int mf = 0; mf < 2; ++mf)
#pragma unroll
            for (int nf = 0; nf < 8; ++nf)
#pragma unroll
                for (int r = 0; r < 4; ++r) {
                    int row = wid * 32 + mf * 16 + g * 4 + r;   // C/D map [m89]
                    int colb = (nf * 32 + ln * 2) ^ ((row & 7) << 4);
                    *reinterpret_cast<ushort*>(lds + row * 256 + colb) = f2bf(acc[mf][nf][r] + b1v[nf]);
                }
    }
    // ---- stage W2s (32KB, linear copy of pre-swizzled w2t) via global_load_lds
#pragma unroll
    for (int i = 0; i < 8; ++i) {
        const char* gs = (const char*)w2t + wid * 8192 + i * 1024 + blane;
        char* ds = lds + 32768 + wid * 8192 + i * 1024;
        __builtin_amdgcn_global_load_lds((const __attribute__((address_space(1))) void*)gs,
                                         (__attribute__((address_space(3))) void*)ds, 16, 0, 0);
    }
    // ---- stage W1es (12x128 f32)
    {
        float* W1es = (float*)(lds + 65536);
        for (int i = t; i < 12 * 128; i += 256)
            W1es[i] = W1[(size_t)(DDIM + (i >> 7)) * HDIM + (i & 127)];
    }
    __syncthreads();                       // Ct + W2s + W1es ready

    // ======== phase B: k2 recurrence, two 64-row passes ========
    const char*  W2s  = lds + 32768;
    const float* W1es = (const float*)(lds + 65536);
    float* stl  = (float*)(lds + 71680);   // [64][2]
    float* redl = (float*)(lds + 72192);   // [8]

    float b2v[8], w30[8], w31[8];
#pragma unroll
    for (int nf = 0; nf < 8; ++nf) {
        b2v[nf] = b2[nf * 16 + ln];
        w30[nf] = W3[(nf * 16 + ln) * 2 + 0];
        w31[nf] = W3[(nf * 16 + ln) * 2 + 1];
    }
    const float b30 = b3[0], b31 = b3[1];
    const bool owner = (ln < 4);
    float lossAcc = 0.f, maskAcc = 0.f;

    for (int p = 0; p < 2; ++p) {
        const int rowLocal = wid * 16 + ln;            // within-pass row (0..63)
        const int ctRow = p * 64 + rowLocal;
        const size_t R_h = row0 + ctRow;
        const int pidx_h = pidx[R_h];

        float scon[32];                                 // base (+b1) + running state contrib
        {
            const int swzr = (rowLocal & 7) << 4;
#pragma unroll
            for (int ks = 0; ks < 4; ++ks) {
                bf16x8 v = *reinterpret_cast<const bf16x8*>(lds + ctRow * 256 + ((ks * 64 + g * 16) ^ swzr));
#pragma unroll
                for (int j = 0; j < 8; ++j) scon[ks * 8 + j] = (float)v[j];
            }
        }
        const int rloc_own = wid * 16 + g * 4 + ln;
        const size_t R_own = row0 + (size_t)p * 64 + rloc_own;
        int pio = 0;
        float ffo[3] = {0,0,0}, ppo[3] = {0,0,0}, mmo[3] = {0,0,0};
        if (owner) {
            pio = pidx[R_own];
#pragma unroll
            for (int q = 0; q < 3; ++q) {
                ffo[q] = freq[R_own * 3 + q];
                ppo[q] = pres[R_own * 3 + q];
                mmo[q] = rmask[R_own * 3 + q];
            }
        }

        for (int s = 0; s < 3; ++s) {
            const int ridx_h = c_perms[pidx_h][s];
            bf16x8 afr[4];
#pragma unroll
            for (int ks = 0; ks < 4; ++ks) {
                const float* ohp = &W1es[(9 + ridx_h) * 128 + ks * 32 + g * 8];
                f32x4 o0 = *reinterpret_cast<const f32x4*>(ohp);
                f32x4 o1 = *reinterpret_cast<const f32x4*>(ohp + 4);
#pragma unroll
                for (int j = 0; j < 4; ++j) {
                    afr[ks][j]     = (__bf16)gelu_fast(scon[ks * 8 + j]     + o0[j]);
                    afr[ks][4 + j] = (__bf16)gelu_fast(scon[ks * 8 + 4 + j] + o1[j]);
                }
            }
            f32x4 acc2[8];
#pragma unroll
            for (int nf = 0; nf < 8; ++nf) acc2[nf] = (f32x4){0.f, 0.f, 0.f, 0.f};
#pragma unroll
            for (int ks = 0; ks < 4; ++ks) {
#pragma unroll
                for (int nf = 0; nf < 8; ++nf) {
                    const int n = nf * 16 + ln;
                    bf16x8 bb = *reinterpret_cast<const bf16x8*>(W2s + n * 256 + ((ks * 64 + g * 16) ^ ((n & 7) << 4)));
                    acc2[nf] = __builtin_amdgcn_mfma_f32_16x16x32_bf16(afr[ks], bb, acc2[nf], 0, 0, 0);
                }
            }
            float p0[4] = {0, 0, 0, 0}, p1[4] = {0, 0, 0, 0};
#pragma unroll
            for (int nf = 0; nf < 8; ++nf) {
#pragma unroll
                for (int r = 0; r < 4; ++r) {
                    float h2 = gelu_fast(acc2[nf][r] + b2v[nf]);
                    p0[r] += h2 * w30[nf];
                    p1[r] += h2 * w31[nf];
                }
            }
#pragma unroll
            for (int mk = 1; mk < 16; mk <<= 1) {
#pragma unroll
                for (int r = 0; r < 4; ++r) {
                    p0[r] += __shfl_xor(p0[r], mk);
                    p1[r] += __shfl_xor(p1[r], mk);
                }
            }
            if (owner) {
                const int ridx_o = c_perms[pio][s];
                float pf = ((ln == 0) ? p0[0] : (ln == 1) ? p0[1] : (ln == 2) ? p0[2] : p0[3]) + b30;
                float z  = ((ln == 0) ? p1[0] : (ln == 1) ? p1[1] : (ln == 2) ? p1[2] : p1[3]) + b31;
                float gt_f = (ridx_o == 0) ? ffo[0] : (ridx_o == 1) ? ffo[1] : ffo[2];
                float gt_p = (ridx_o == 0) ? ppo[0] : (ridx_o == 1) ? ppo[1] : ppo[2];
                float m    = (ridx_o == 0) ? mmo[0] : (ridx_o == 1) ? mmo[1] : mmo[2];
                float d = pf - gt_f;
                float pl = (fmaxf(z, 0.f) - z * gt_p + __logf(1.0f + __expf(-fabsf(z)))) * m;
                lossAcc += d * d * m + pl;
                maskAcc += m;
                bool msk = m > 0.5f;
                float act_f = msk ? pf : gt_f;
                float act_p = msk ? (1.f / (1.f + __expf(-z))) : gt_p;
                stl[rloc_own * 2 + 0] = act_f;
                stl[rloc_own * 2 + 1] = act_p;
                dec_f[R_own * 3 + ridx_o] = act_f;
                dec_p[R_own * 3 + ridx_o] = act_p;
            }
            if (s < 2) {   // same-wave LDS exchange; DS in-order per wave
                float af = stl[rowLocal * 2 + 0];
                float ap = stl[rowLocal * 2 + 1];
                const float* w0r = &W1es[(ridx_h * 3 + 0) * 128];
                const float* w1r = &W1es[(ridx_h * 3 + 1) * 128];
                const float* w2r = &W1es[(ridx_h * 3 + 2) * 128];
#pragma unroll
                for (int ks = 0; ks < 4; ++ks) {
                    const int c0 = ks * 32 + g * 8;
                    f32x4 a0 = *reinterpret_cast<const f32x4*>(w0r + c0);
                    f32x4 a1 = *reinterpret_cast<const f32x4*>(w0r + c0 + 4);
                    f32x4 b0 = *reinterpret_cast<const f32x4*>(w1r + c0);
                    f32x4 b1x = *reinterpret_cast<const f32x4*>(w1r + c0 + 4);
                    f32x4 c0v = *reinterpret_cast<const f32x4*>(w2r + c0);
                    f32x4 c1v = *reinterpret_cast<const f32x4*>(w2r + c0 + 4);
#pragma unroll
                    for (int j = 0; j < 4; ++j) {
                        scon[ks * 8 + j]     += af * a0[j] + ap * b0[j]  + c0v[j];
                        scon[ks * 8 + 4 + j] += af * a1[j] + ap * b1x[j] + c1v[j];
                    }
                }
            }
        }
    }
    // ---- deterministic loss reduction
#pragma unroll
    for (int mk = 1; mk < 64; mk <<= 1) {
        lossAcc += __shfl_xor(lossAcc, mk);
        maskAcc += __shfl_xor(maskAcc, mk);
    }
    if (lane == 0) { redl[wid * 2] = lossAcc; redl[wid * 2 + 1] = maskAcc; }
    __syncthreads();
    if (t == 0) {
        float ls = 0.f, ms = 0.f;
#pragma unroll
        for (int w = 0; w < 4; ++w) { ls += redl[w * 2]; ms += redl[w * 2 + 1]; }
        partials[2 * (size_t)blockIdx.x]     = ls;
        partials[2 * (size_t)blockIdx.x + 1] = ms;
    }
}

// ---------------- K3: deterministic final reduction ----------------
__global__ __launch_bounds__(256) void k3_reduce(const float* __restrict__ partials,
                                                 int nb, float* __restrict__ out)
{
    __shared__ float sl[256], sm[256];
    int t = threadIdx.x;
    float ls = 0.f, ms = 0.f;
    for (int i = t; i < nb; i += 256) { ls += partials[2 * i]; ms += partials[2 * i + 1]; }
    sl[t] = ls; sm[t] = ms;
    __syncthreads();
    for (int s = 128; s > 0; s >>= 1) {
        if (t < s) { sl[t] += sl[t + s]; sm[t] += sm[t + s]; }
        __syncthreads();
    }
    if (t == 0) out[0] = sl[0] / (sm[0] + 1e-8f);
}

extern "C" void kernel_launch(void* const* d_in, const int* in_sizes, int n_in,
                              void* d_out, int out_size, void* d_ws, size_t ws_size,
                              hipStream_t stream) {
    const float* seq   = (const float*)d_in[0];
    const float* freq  = (const float*)d_in[1];
    const float* pres  = (const float*)d_in[2];
    const float* rmask = (const float*)d_in[3];
    const int*   pidx  = (const int*)d_in[4];
    const float* W1    = (const float*)d_in[5];
    const float* b1    = (const float*)d_in[6];
    const float* W2    = (const float*)d_in[7];
    const float* b2    = (const float*)d_in[8];
    const float* W3    = (const float*)d_in[9];
    const float* b3    = (const float*)d_in[10];

    int B = in_sizes[4];
    float* out   = (float*)d_out;
    float* dec_f = out + 1;
    float* dec_p = out + 1 + (size_t)B * 3;

    char* ws = (char*)d_ws;
    float*  partials = (float*)ws;                        // 16 KB reserved
    ushort* w1s  = (ushort*)(ws + 16384);                 // 256 KB
    ushort* w2t  = (ushort*)(ws + 16384 + 262144);        // 32 KB

    int nblk = B / 128;                                   // 1024
    k0_prep<<<(DDIM * HDIM + HDIM * HDIM + 255) / 256, 256, 0, stream>>>(W1, W2, w1s, w2t);
    kf_fused<<<nblk, 256, 0, stream>>>(seq, w1s, w2t, freq, pres, rmask, pidx,
                                       W1, b1, b2, W3, b3, dec_f, dec_p, partials);
    k3_reduce<<<1, 256, 0, stream>>>(partials, nblk, out);
}